// Round 10
// baseline (214.514 us; speedup 1.0000x reference)
//
#include <hip/hip_runtime.h>
#include <hip/hip_fp16.h>
#include <math.h>

#define NN 50000
#define NE 800000
#define DD 128

#define NB  196      // buckets of 256 nodes (dst >> 8)
#define CAP 5300     // per-bucket capacity (mean 4082, sd 64)
#define EPB 4096     // edges per phase-A block
#define A_BLOCKS 196 // ceil(NE/EPB)
#define GEMM_B 782   // ceil(NN/64)
#define ZERO_B 98    // ceil(100000 floats / 1024)
#define LPAD 136
#define CSTRIDE 256  // row stride of cnts/offs tables

#define SLAB2 (NN * 64)   // halves per 64-feature chunk slab (6.4 MB); 2 chunks

#define FRONT_SMEM (DD * LPAD * 2 + 64 * LPAD * 2)   // 52224 B (gemm role is the max)

typedef _Float16 half8_t __attribute__((ext_vector_type(8)));
typedef float f32x4 __attribute__((ext_vector_type(4)));

// ---------------- node 1: phaseA binning (no atomics) || gemm1 (G1 = X·W1) || zero-out ----------------

__global__ __launch_bounds__(256) void k_front(const int* __restrict__ src, const int* __restrict__ dst,
                                               unsigned int* __restrict__ ebuf2,
                                               int* __restrict__ cnts_g, int* __restrict__ offs_g,
                                               const float* __restrict__ X, const float* __restrict__ W1,
                                               __half* __restrict__ G1,
                                               float* __restrict__ outz, int zcount) {
    __shared__ __align__(16) char smem[FRONT_SMEM];
    const int blk = blockIdx.x;
    const int tid = threadIdx.x;

    if (blk < A_BLOCKS) {
        // ---- phase A: bin 4096 edges into bucket-major order within this block's own segment ----
        int* hist          = (int*)smem;
        int* scanbuf       = hist + 256;
        unsigned int* stage = (unsigned int*)(smem + 2048);   // EPB uints = 16 KB

        const int e0 = blk * EPB;
        int nE = NE - e0; if (nE > EPB) nE = EPB;

        hist[tid] = 0;
        __syncthreads();

        unsigned int pk[16];
        unsigned int br[16];   // bucket(8b) | rank<<8
        #pragma unroll
        for (int j = 0; j < 16; ++j) {
            int idx = tid + j * 256;
            if (idx < nE) {
                int e = e0 + idx;
                int s = src[e], d = dst[e];
                int b = d >> 8;
                int r = atomicAdd(&hist[b], 1);
                pk[j] = (unsigned int)s | ((unsigned int)(d & 255) << 16);
                br[j] = (unsigned int)b | ((unsigned int)r << 8);
            }
        }
        __syncthreads();
        int v = hist[tid];
        scanbuf[tid] = v;
        __syncthreads();
        for (int o = 1; o < 256; o <<= 1) {
            int t2 = (tid >= o) ? scanbuf[tid - o] : 0;
            __syncthreads();
            scanbuf[tid] += t2;
            __syncthreads();
        }
        int base_excl = scanbuf[tid] - v;
        if (tid < NB) {
            cnts_g[blk * CSTRIDE + tid] = v;
            offs_g[blk * CSTRIDE + tid] = base_excl;
        }
        hist[tid] = base_excl;
        __syncthreads();

        #pragma unroll
        for (int j = 0; j < 16; ++j) {
            int idx = tid + j * 256;
            if (idx < nE) {
                int b = br[j] & 255;
                int r = (int)(br[j] >> 8);
                stage[hist[b] + r] = pk[j];
            }
        }
        __syncthreads();
        #pragma unroll
        for (int j = 0; j < 16; ++j) {
            int idx = tid + j * 256;
            if (idx < nE) ebuf2[(size_t)blk * EPB + idx] = stage[idx];   // fully coalesced dump
        }
    } else if (blk < A_BLOCKS + GEMM_B) {
        // ---- gemm1: G1 = X (fp32) @ W1 (fp32, transposed in-LDS), fp16 slab output, NO dinv ----
        __half* Wl = (__half*)smem;                        // [DD][LPAD]
        __half* Al = (__half*)(smem + DD * LPAD * 2);      // [64][LPAD]
        const int row0 = (blk - A_BLOCKS) * 64;

        {   // W1[k][n] -> Wl[n][k] half (scatter transpose)
            const float4* W4 = (const float4*)W1;          // 4096 float4
            #pragma unroll
            for (int j = 0; j < 16; ++j) {
                int u = tid + j * 256;
                int k = u >> 5, n4 = (u & 31) * 4;
                float4 wv = W4[u];
                Wl[(n4 + 0) * LPAD + k] = __float2half(wv.x);
                Wl[(n4 + 1) * LPAD + k] = __float2half(wv.y);
                Wl[(n4 + 2) * LPAD + k] = __float2half(wv.z);
                Wl[(n4 + 3) * LPAD + k] = __float2half(wv.w);
            }
        }
        {   // X rows fp32 -> half in LDS
            const float4* X4 = (const float4*)X;
            #pragma unroll
            for (int j = 0; j < 8; ++j) {
                int u = tid + j * 256;             // 0..2047
                int r = u >> 5, c4 = u & 31;
                int grow = row0 + r;
                float4 v = make_float4(0.f, 0.f, 0.f, 0.f);
                if (grow < NN) v = X4[(size_t)grow * 32 + c4];
                __half2 a = __floats2half2_rn(v.x, v.y);
                __half2 b = __floats2half2_rn(v.z, v.w);
                uint2 pkk;
                pkk.x = *(unsigned int*)&a;
                pkk.y = *(unsigned int*)&b;
                *(uint2*)&Al[r * LPAD + c4 * 4] = pkk;
            }
        }
        __syncthreads();

        const int wave = tid >> 6;
        const int lane = tid & 63;
        const int m    = lane & 15;
        const int quad = lane >> 4;

        f32x4 acc[8];
        #pragma unroll
        for (int t = 0; t < 8; ++t) acc[t] = (f32x4){0.f, 0.f, 0.f, 0.f};

        #pragma unroll
        for (int kk = 0; kk < DD; kk += 32) {
            half8_t a = *(const half8_t*)&Al[(wave * 16 + m) * LPAD + kk + quad * 8];
            #pragma unroll
            for (int t = 0; t < 8; ++t) {
                half8_t b = *(const half8_t*)&Wl[(t * 16 + m) * LPAD + kk + quad * 8];
                acc[t] = __builtin_amdgcn_mfma_f32_16x16x32_f16(a, b, acc[t], 0, 0, 0);
            }
        }
        __syncthreads();

        #pragma unroll
        for (int t = 0; t < 8; ++t) {
            #pragma unroll
            for (int r = 0; r < 4; ++r) {
                int row_l = wave * 16 + quad * 4 + r;
                int c     = t * 16 + m;
                Al[row_l * LPAD + c] = __float2half(acc[t][r]);
            }
        }
        __syncthreads();

        #pragma unroll
        for (int j = 0; j < 4; ++j) {
            int u = tid + j * 256;
            int r = u >> 4, c16 = u & 15;
            int ch = c16 >> 3, wi = c16 & 7;
            int grow = row0 + r;
            if (grow < NN) {
                uint4 v = *(const uint4*)&Al[r * LPAD + c16 * 8];
                *(uint4*)(G1 + (size_t)ch * SLAB2 + (size_t)grow * 64 + wi * 8) = v;
            }
        }
    } else {
        // ---- zero `out` (must precede agg2's atomics; graph order guarantees it) ----
        int idx = (blk - A_BLOCKS - GEMM_B) * 256 + tid;
        if (idx * 4 + 3 < zcount) ((float4*)outz)[idx] = make_float4(0.f, 0.f, 0.f, 0.f);
        else {
            for (int k = idx * 4; k < zcount; ++k) outz[k] = 0.f;
        }
    }
}

// ---------------- node 2: csr build from per-block tables (512 threads, 1 block/bucket) ----------------

__global__ __launch_bounds__(512) void k_csr(const unsigned int* __restrict__ ebuf2,
                                             const int* __restrict__ cnts_g, const int* __restrict__ offs_g,
                                             int* __restrict__ row_ptr, float* __restrict__ dinv,
                                             unsigned short* __restrict__ col) {
    __shared__ int colcnt[256];
    __shared__ int runoff[256];
    __shared__ int sizes[256];
    __shared__ int cnt[256];
    __shared__ int scanb[256];
    __shared__ unsigned int stage32[CAP];
    __shared__ unsigned short colst[CAP];

    const int b   = blockIdx.x;
    const int tid = threadIdx.x;
    const int n0  = b << 8;
    int nb = NN - n0; if (nb > 256) nb = 256;

    // bucket sizes (all) + this bucket's per-source-block run lengths
    if (tid < 256) {
        int s = 0;
        if (tid < NB) {
            for (int k = 0; k < NB; ++k) s += cnts_g[k * CSTRIDE + tid];
        }
        sizes[tid]  = s;
        colcnt[tid] = (tid < NB) ? cnts_g[tid * CSTRIDE + b] : 0;
    }
    __syncthreads();
    const int sb = sizes[b];

    // rbase = exclusive prefix of sizes at b
    if (tid < 256) scanb[tid] = sizes[tid];
    __syncthreads();
    for (int o = 1; o < 256; o <<= 1) {
        int t = 0;
        if (tid < 256 && tid >= o) t = scanb[tid - o];
        __syncthreads();
        if (tid < 256) scanb[tid] += t;
        __syncthreads();
    }
    const int rbase = scanb[b] - sb;
    __syncthreads();

    // runoff = exclusive prefix of colcnt
    if (tid < 256) scanb[tid] = colcnt[tid];
    __syncthreads();
    for (int o = 1; o < 256; o <<= 1) {
        int t = 0;
        if (tid < 256 && tid >= o) t = scanb[tid - o];
        __syncthreads();
        if (tid < 256) scanb[tid] += t;
        __syncthreads();
    }
    if (tid < 256) runoff[tid] = scanb[tid] - colcnt[tid];
    __syncthreads();

    // gather this bucket's runs from the 196 block segments
    if (tid < NB) {
        int len = colcnt[tid];
        const unsigned int* s = ebuf2 + (size_t)tid * EPB + offs_g[tid * CSTRIDE + b];
        unsigned int* d = stage32 + runoff[tid];
        for (int i = 0; i < len; ++i) d[i] = s[i];
    }
    __syncthreads();

    // per-node histogram
    if (tid < 256) cnt[tid] = 0;
    __syncthreads();
    for (int p = tid; p < sb; p += 512) {
        atomicAdd(&cnt[(stage32[p] >> 16) & 255], 1);
    }
    __syncthreads();
    int v = (tid < 256) ? cnt[tid] : 0;
    if (tid < 256) scanb[tid] = v;
    __syncthreads();
    for (int o = 1; o < 256; o <<= 1) {
        int t = 0;
        if (tid < 256 && tid >= o) t = scanb[tid - o];
        __syncthreads();
        if (tid < 256) scanb[tid] += t;
        __syncthreads();
    }
    int excl = (tid < 256) ? (scanb[tid] - v) : 0;
    if (tid < nb) {
        row_ptr[n0 + tid] = rbase + excl;
        dinv[n0 + tid] = rsqrtf(1.0f + (float)v);
    }
    if (b == 0 && tid == 0) row_ptr[NN] = NE;
    if (tid < 256) cnt[tid] = excl;
    __syncthreads();
    for (int p = tid; p < sb; p += 512) {
        unsigned int e = stage32[p];
        int pos = atomicAdd(&cnt[(e >> 16) & 255], 1);
        colst[pos] = (unsigned short)(e & 0xFFFFu);
    }
    __syncthreads();
    for (int p = tid; p < sb; p += 512) {
        col[rbase + p] = colst[p];
    }
}

// ---------------- node 4: gemm2 (G2 = H1·W2, fp16 slabs, W2 self-transposed, NO dinv) ----------------

__global__ __launch_bounds__(256) void k_gemm2(const __half* __restrict__ Xc, const float* __restrict__ W2,
                                               __half* __restrict__ Gc) {
    __shared__ __half Wl[DD * LPAD];
    __shared__ __half Al[64 * LPAD];

    const int tid  = threadIdx.x;
    const int row0 = blockIdx.x * 64;

    {   // W2[k][n] -> Wl[n][k] half
        const float4* W4 = (const float4*)W2;
        #pragma unroll
        for (int j = 0; j < 16; ++j) {
            int u = tid + j * 256;
            int k = u >> 5, n4 = (u & 31) * 4;
            float4 wv = W4[u];
            Wl[(n4 + 0) * LPAD + k] = __float2half(wv.x);
            Wl[(n4 + 1) * LPAD + k] = __float2half(wv.y);
            Wl[(n4 + 2) * LPAD + k] = __float2half(wv.z);
            Wl[(n4 + 3) * LPAD + k] = __float2half(wv.w);
        }
    }
    {
        #pragma unroll
        for (int j = 0; j < 4; ++j) {
            int u = tid + j * 256;
            int r = u >> 4, c16 = u & 15;
            int ch = c16 >> 3, wi = c16 & 7;
            int grow = row0 + r;
            uint4 v;
            if (grow < NN) v = *(const uint4*)(Xc + (size_t)ch * SLAB2 + (size_t)grow * 64 + wi * 8);
            else { v.x = 0; v.y = 0; v.z = 0; v.w = 0; }
            *(uint4*)&Al[r * LPAD + c16 * 8] = v;
        }
    }
    __syncthreads();

    const int wave = tid >> 6;
    const int lane = tid & 63;
    const int m    = lane & 15;
    const int quad = lane >> 4;

    f32x4 acc[8];
    #pragma unroll
    for (int t = 0; t < 8; ++t) acc[t] = (f32x4){0.f, 0.f, 0.f, 0.f};

    #pragma unroll
    for (int kk = 0; kk < DD; kk += 32) {
        half8_t a = *(const half8_t*)&Al[(wave * 16 + m) * LPAD + kk + quad * 8];
        #pragma unroll
        for (int t = 0; t < 8; ++t) {
            half8_t b = *(const half8_t*)&Wl[(t * 16 + m) * LPAD + kk + quad * 8];
            acc[t] = __builtin_amdgcn_mfma_f32_16x16x32_f16(a, b, acc[t], 0, 0, 0);
        }
    }
    __syncthreads();

    #pragma unroll
    for (int t = 0; t < 8; ++t) {
        #pragma unroll
        for (int r = 0; r < 4; ++r) {
            int row_l = wave * 16 + quad * 4 + r;
            int c     = t * 16 + m;
            Al[row_l * LPAD + c] = __float2half(acc[t][r]);
        }
    }
    __syncthreads();

    #pragma unroll
    for (int j = 0; j < 4; ++j) {
        int u = tid + j * 256;
        int r = u >> 4, c16 = u & 15;
        int ch = c16 >> 3, wi = c16 & 7;
        int grow = row0 + r;
        if (grow < NN) {
            uint4 v = *(const uint4*)&Al[r * LPAD + c16 * 8];
            *(uint4*)(Gc + (size_t)ch * SLAB2 + (size_t)grow * 64 + wi * 8) = v;
        }
    }
}

// ---------------- aggregation: 16-lane group per node, 64-feat chunks, per-edge dinv ----------------

__device__ inline float4 h4_to_f4(uint2 r) {
    __half2 a = *(__half2*)&r.x;
    __half2 b = *(__half2*)&r.y;
    float2 lo = __half22float2(a), hi = __half22float2(b);
    return make_float4(lo.x, lo.y, hi.x, hi.y);
}

__device__ inline uint2 f4_to_h4(float4 v) {
    __half2 a = __floats2half2_rn(v.x, v.y);
    __half2 b = __floats2half2_rn(v.z, v.w);
    uint2 r;
    r.x = *(unsigned int*)&a;
    r.y = *(unsigned int*)&b;
    return r;
}

// returns T = d_i*G[i] + sum_s d_s*G[s]  (caller applies final d_i and bias)
__device__ inline float4 gather_grp64(const __half* __restrict__ slab, const float* __restrict__ dinv,
                                      float di, int node, int fl,
                                      const unsigned short* __restrict__ col, int beg, int end) {
    const __half* base = slab + fl * 4;
    float4 sv = h4_to_f4(*(const uint2*)(base + (size_t)node * 64));
    float4 accA = make_float4(di * sv.x, di * sv.y, di * sv.z, di * sv.w);
    float4 accB = make_float4(0.f, 0.f, 0.f, 0.f);
    int p = beg;
    for (; p + 3 < end; p += 4) {
        int s0 = col[p], s1 = col[p + 1], s2 = col[p + 2], s3 = col[p + 3];
        float d0 = dinv[s0], d1 = dinv[s1], d2 = dinv[s2], d3 = dinv[s3];
        float4 v0 = h4_to_f4(*(const uint2*)(base + (size_t)s0 * 64));
        float4 v1 = h4_to_f4(*(const uint2*)(base + (size_t)s1 * 64));
        float4 v2 = h4_to_f4(*(const uint2*)(base + (size_t)s2 * 64));
        float4 v3 = h4_to_f4(*(const uint2*)(base + (size_t)s3 * 64));
        accA.x = fmaf(d0, v0.x, fmaf(d1, v1.x, accA.x));
        accA.y = fmaf(d0, v0.y, fmaf(d1, v1.y, accA.y));
        accA.z = fmaf(d0, v0.z, fmaf(d1, v1.z, accA.z));
        accA.w = fmaf(d0, v0.w, fmaf(d1, v1.w, accA.w));
        accB.x = fmaf(d2, v2.x, fmaf(d3, v3.x, accB.x));
        accB.y = fmaf(d2, v2.y, fmaf(d3, v3.y, accB.y));
        accB.z = fmaf(d2, v2.z, fmaf(d3, v3.z, accB.z));
        accB.w = fmaf(d2, v2.w, fmaf(d3, v3.w, accB.w));
    }
    for (; p < end; ++p) {
        int s0 = col[p];
        float d0 = dinv[s0];
        float4 v0 = h4_to_f4(*(const uint2*)(base + (size_t)s0 * 64));
        accA.x = fmaf(d0, v0.x, accA.x);
        accA.y = fmaf(d0, v0.y, accA.y);
        accA.z = fmaf(d0, v0.z, accA.z);
        accA.w = fmaf(d0, v0.w, accA.w);
    }
    accA.x += accB.x; accA.y += accB.y; accA.z += accB.z; accA.w += accB.w;
    return accA;
}

__global__ __launch_bounds__(256) void k_aggregate_c(const __half* __restrict__ G, const float* __restrict__ dinv,
                                                     const int* __restrict__ row_ptr, const unsigned short* __restrict__ col,
                                                     const float* __restrict__ bias, __half* __restrict__ H) {
    const int bx    = blockIdx.x;
    const int slot  = bx & 7;
    const int chunk = slot >> 2;
    const int nb    = (bx >> 3) * 4 + (slot & 3);
    const int g     = threadIdx.x >> 4;
    const int fl    = threadIdx.x & 15;
    const int node  = nb * 16 + g;
    if (node >= NN) return;

    const __half* slab = G + (size_t)chunk * SLAB2;
    int beg = row_ptr[node];
    int end = row_ptr[node + 1];
    float di = dinv[node];
    float4 acc = gather_grp64(slab, dinv, di, node, fl, col, beg, end);

    float4 bv = *(const float4*)(bias + chunk * 64 + fl * 4);
    float4 hv;
    hv.x = fmaxf(fmaf(di, acc.x, bv.x), 0.f);
    hv.y = fmaxf(fmaf(di, acc.y, bv.y), 0.f);
    hv.z = fmaxf(fmaf(di, acc.z, bv.z), 0.f);
    hv.w = fmaxf(fmaf(di, acc.w, bv.w), 0.f);
    *(uint2*)(H + (size_t)chunk * SLAB2 + (size_t)node * 64 + fl * 4) = f4_to_h4(hv);
}

__global__ __launch_bounds__(256) void k_aggregate_heads_c(const __half* __restrict__ G, const float* __restrict__ dinv,
                                                           const int* __restrict__ row_ptr, const unsigned short* __restrict__ col,
                                                           const float* __restrict__ bias,
                                                           const float* __restrict__ Wt, const float* __restrict__ bt,
                                                           const float* __restrict__ We, const float* __restrict__ be,
                                                           float* __restrict__ out) {
    const int bx    = blockIdx.x;
    const int slot  = bx & 7;
    const int chunk = slot >> 2;
    const int nb    = (bx >> 3) * 4 + (slot & 3);
    const int g     = threadIdx.x >> 4;
    const int fl    = threadIdx.x & 15;
    const int node  = nb * 16 + g;
    if (node >= NN) return;

    const __half* slab = G + (size_t)chunk * SLAB2;
    int beg = row_ptr[node];
    int end = row_ptr[node + 1];
    float di = dinv[node];
    float4 acc = gather_grp64(slab, dinv, di, node, fl, col, beg, end);

    float4 bv = *(const float4*)(bias + chunk * 64 + fl * 4);
    float hx = fmaxf(fmaf(di, acc.x, bv.x), 0.f);
    float hy = fmaxf(fmaf(di, acc.y, bv.y), 0.f);
    float hz = fmaxf(fmaf(di, acc.z, bv.z), 0.f);
    float hw = fmaxf(fmaf(di, acc.w, bv.w), 0.f);

    float4 wt = *(const float4*)(Wt + chunk * 64 + fl * 4);
    float4 we = *(const float4*)(We + chunk * 64 + fl * 4);
    float t  = hx * wt.x + hy * wt.y + hz * wt.z + hw * wt.w;
    float ev = hx * we.x + hy * we.y + hz * we.z + hw * we.w;
    #pragma unroll
    for (int o = 1; o < 16; o <<= 1) {
        t  += __shfl_xor(t, o, 64);
        ev += __shfl_xor(ev, o, 64);
    }
    if (fl == 0) {
        if (chunk == 0) { t += bt[0]; ev += be[0]; }
        atomicAdd(&out[node], t);
        atomicAdd(&out[NN + node], ev);
    }
}

// ---------------- launch: 5 graph nodes, no memsets ----------------

extern "C" void kernel_launch(void* const* d_in, const int* in_sizes, int n_in,
                              void* d_out, int out_size, void* d_ws, size_t ws_size,
                              hipStream_t stream) {
    const float* x  = (const float*)d_in[0];
    const int*   ei = (const int*)d_in[1];
    const float* W1 = (const float*)d_in[2];
    const float* b1 = (const float*)d_in[3];
    const float* W2 = (const float*)d_in[4];
    const float* b2 = (const float*)d_in[5];
    const float* Wt = (const float*)d_in[6];
    const float* bt = (const float*)d_in[7];
    const float* We = (const float*)d_in[8];
    const float* be = (const float*)d_in[9];
    float* out = (float*)d_out;

    const int* srcI = ei;
    const int* dstI = ei + NE;

    char* w = (char*)d_ws;
    __half*         Gh    = (__half*)w;         w += (size_t)NN * DD * sizeof(__half);        // 12.8 MB (2 slabs)
    __half*         H1h   = (__half*)w;         w += (size_t)NN * DD * sizeof(__half);        // 12.8 MB (2 slabs)
    unsigned int*   ebuf2 = (unsigned int*)w;   w += (size_t)A_BLOCKS * EPB * sizeof(unsigned int); // 3.2 MB
    unsigned short* col   = (unsigned short*)w; w += (size_t)NE * sizeof(unsigned short);     // 1.6 MB
    float*          dinv  = (float*)w;          w += (size_t)(NN + 64) * sizeof(float);
    int*            rowp  = (int*)w;            w += (size_t)(NN + 1) * sizeof(int);
    int*            cnts  = (int*)w;            w += (size_t)A_BLOCKS * CSTRIDE * sizeof(int); // 200 KB
    int*            offs  = (int*)w;            w += (size_t)A_BLOCKS * CSTRIDE * sizeof(int); // 200 KB

    const int FRONT_B = A_BLOCKS + GEMM_B + ZERO_B;   // 1076
    const int NBLK    = (NN + 15) / 16;               // 3125
    const int AGG_B   = ((NBLK + 3) / 4) * 8;         // 6256

    hipLaunchKernelGGL(k_front, dim3(FRONT_B), dim3(256), 0, stream,
                       srcI, dstI, ebuf2, cnts, offs, x, W1, Gh, out, out_size);
    hipLaunchKernelGGL(k_csr,   dim3(NB),      dim3(512), 0, stream, ebuf2, cnts, offs, rowp, dinv, col);

    hipLaunchKernelGGL(k_aggregate_c, dim3(AGG_B), dim3(256), 0, stream, Gh, dinv, rowp, col, b1, H1h);
    hipLaunchKernelGGL(k_gemm2,       dim3(GEMM_B), dim3(256), 0, stream, H1h, W2, Gh);
    hipLaunchKernelGGL(k_aggregate_heads_c, dim3(AGG_B), dim3(256), 0, stream, Gh, dinv, rowp, col, b2,
                       Wt, bt, We, be, out);
}

// Round 11
// 202.474 us; speedup vs baseline: 1.0595x; 1.0595x over previous
//
#include <hip/hip_runtime.h>
#include <hip/hip_fp16.h>
#include <math.h>

#define NN 50000
#define NE 800000
#define DD 128

#define NB  196      // buckets of 256 nodes (dst >> 8)
#define CAP 5300     // per-bucket segment capacity (mean 4096, sd 64 -> +19 sigma)
#define EPB 4096     // edges per phase-A block
#define A_BLOCKS 196 // ceil(NE/EPB)

#define SLAB2 (NN * 64)   // halves per 64-feature chunk slab (6.4 MB); 2 chunks

typedef _Float16 half8_t __attribute__((ext_vector_type(8)));
typedef float f32x4 __attribute__((ext_vector_type(4)));

// ---------------- fused setup: phaseA edge binning || W transpose ----------------
// bcnt must be zeroed before launch.

__global__ __launch_bounds__(256) void k_setup(const int* __restrict__ src, const int* __restrict__ dst,
                                               int* __restrict__ bcnt, unsigned int* __restrict__ ebuf,
                                               const float* __restrict__ W1, const float* __restrict__ W2,
                                               __half* __restrict__ WT1, __half* __restrict__ WT2) {
    const int blk = blockIdx.x;
    const int tid = threadIdx.x;

    if (blk < A_BLOCKS) {
        // ---- phase A: bin edges into bucket segments; packed = src | (dst&255)<<16 ----
        __shared__ int hist[256];
        __shared__ int scanbuf[256];
        __shared__ int gbase[256];
        __shared__ unsigned int stage[EPB];
        __shared__ int tgt[EPB];

        const int e0 = blk * EPB;
        int nE = NE - e0; if (nE > EPB) nE = EPB;

        hist[tid] = 0;
        __syncthreads();

        unsigned int pk[16];
        unsigned int br[16];   // bucket(8b) | rank<<8
        #pragma unroll
        for (int j = 0; j < 16; ++j) {
            int idx = tid + j * 256;
            if (idx < nE) {
                int e = e0 + idx;
                int s = src[e], d = dst[e];
                int b = d >> 8;
                int r = atomicAdd(&hist[b], 1);
                pk[j] = (unsigned int)s | ((unsigned int)(d & 255) << 16);
                br[j] = (unsigned int)b | ((unsigned int)r << 8);
            }
        }
        __syncthreads();
        int v = hist[tid];
        scanbuf[tid] = v;
        __syncthreads();
        for (int o = 1; o < 256; o <<= 1) {
            int t2 = (tid >= o) ? scanbuf[tid - o] : 0;
            __syncthreads();
            scanbuf[tid] += t2;
            __syncthreads();
        }
        int base_excl = scanbuf[tid] - v;
        if (tid < NB && v > 0) gbase[tid] = tid * CAP + atomicAdd(&bcnt[tid], v);
        hist[tid] = base_excl;
        __syncthreads();

        #pragma unroll
        for (int j = 0; j < 16; ++j) {
            int idx = tid + j * 256;
            if (idx < nE) {
                int b = br[j] & 255;
                int r = (int)(br[j] >> 8);
                int pos = hist[b] + r;
                stage[pos] = pk[j];
                tgt[pos]   = gbase[b] + r;
            }
        }
        __syncthreads();
        #pragma unroll
        for (int j = 0; j < 16; ++j) {
            int idx = tid + j * 256;
            if (idx < nE) ebuf[tgt[idx]] = stage[idx];
        }
    } else {
        // ---- W1/W2 -> fp16 transposed WT[n][k] ----
        const float* W  = (blk == A_BLOCKS) ? W1 : W2;
        __half*      WT = (blk == A_BLOCKS) ? WT1 : WT2;
        int n = tid >> 1;
        int k0 = (tid & 1) * 64;
        #pragma unroll 8
        for (int j = 0; j < 64; ++j) {
            int k = k0 + j;
            WT[n * DD + k] = __float2half(W[k * DD + n]);
        }
    }
}

// ---------------- Phase B: per-bucket CSR; 512 threads; coalesced ushort col flush ----------------

__global__ __launch_bounds__(512) void k_build_csr(const unsigned int* __restrict__ ebuf,
                                                   const int* __restrict__ bcnt,
                                                   int* __restrict__ row_ptr,
                                                   float* __restrict__ dinv,
                                                   unsigned short* __restrict__ col) {
    __shared__ int cnt[256];
    __shared__ int scanb[256];
    __shared__ unsigned short stage[CAP];

    const int b   = blockIdx.x;
    const int tid = threadIdx.x;
    const int seg0 = b * CAP;
    const int sb   = bcnt[b];
    const int n0   = b << 8;
    int nb = NN - n0; if (nb > 256) nb = 256;

    // rbase = sum of bucket sizes below b (scan over NB in first 256 lanes)
    if (tid < 256) scanb[tid] = (tid < NB) ? bcnt[tid] : 0;
    __syncthreads();
    for (int o = 1; o < 256; o <<= 1) {
        int t = 0;
        if (tid < 256 && tid >= o) t = scanb[tid - o];
        __syncthreads();
        if (tid < 256) scanb[tid] += t;
        __syncthreads();
    }
    const int rbase = scanb[b] - sb;
    __syncthreads();

    if (tid < 256) cnt[tid] = 0;
    __syncthreads();
    for (int p = tid; p < sb; p += 512) {
        unsigned int e = ebuf[seg0 + p];
        atomicAdd(&cnt[(e >> 16) & 255], 1);
    }
    __syncthreads();
    int v = (tid < 256) ? cnt[tid] : 0;
    if (tid < 256) scanb[tid] = v;
    __syncthreads();
    for (int o = 1; o < 256; o <<= 1) {
        int t = 0;
        if (tid < 256 && tid >= o) t = scanb[tid - o];
        __syncthreads();
        if (tid < 256) scanb[tid] += t;
        __syncthreads();
    }
    int excl = (tid < 256) ? (scanb[tid] - v) : 0;
    if (tid < nb) {
        row_ptr[n0 + tid] = rbase + excl;
        dinv[n0 + tid] = rsqrtf(1.0f + (float)v);
    }
    if (b == 0 && tid == 0) row_ptr[NN] = NE;
    if (tid < 256) cnt[tid] = excl;
    __syncthreads();
    for (int p = tid; p < sb; p += 512) {
        unsigned int e = ebuf[seg0 + p];
        int pos = atomicAdd(&cnt[(e >> 16) & 255], 1);
        stage[pos] = (unsigned short)(e & 0xFFFFu);
    }
    __syncthreads();
    for (int p = tid; p < sb; p += 512) {
        col[rbase + p] = stage[p];
    }
}

// ---------------- MFMA GEMM (layer 1): fp32 input, converts during staging; zero-tail ----------------

#define LPAD 136
#define GEMM_B 782          // ceil(NN/64)
#define ZERO_B 98           // ceil(100000 floats / (256*4))

__global__ __launch_bounds__(256) void k_gemm_x(const float* __restrict__ X, const __half* __restrict__ WT,
                                                const float* __restrict__ dinv, __half* __restrict__ Gc,
                                                float* __restrict__ zbuf, int zcount) {
    const int tid = threadIdx.x;

    if (blockIdx.x >= GEMM_B) {
        int idx = (blockIdx.x - GEMM_B) * 256 + tid;   // float4 index
        if (idx * 4 + 3 < zcount) ((float4*)zbuf)[idx] = make_float4(0.f, 0.f, 0.f, 0.f);
        else {
            for (int k = idx * 4; k < zcount; ++k) zbuf[k] = 0.f;
        }
        return;
    }

    __shared__ __half Wl[DD * LPAD];
    __shared__ __half Al[64 * LPAD];

    const int row0 = blockIdx.x * 64;

    {
        const uint4* WTg = (const uint4*)WT;
        #pragma unroll
        for (int j = 0; j < 8; ++j) {
            int u = tid + j * 256;
            int n = u >> 4, koff = (u & 15) * 8;
            uint4 v = WTg[u];
            *(uint4*)&Wl[n * LPAD + koff] = v;
        }
    }
    {
        // stage 64 rows x 128 fp32 features -> half in LDS. 2048 float4 units.
        const float4* X4 = (const float4*)X;
        #pragma unroll
        for (int j = 0; j < 8; ++j) {
            int u = tid + j * 256;             // 0..2047
            int r = u >> 5, c4 = u & 31;       // row, float4-within-row
            int grow = row0 + r;
            float4 v = make_float4(0.f, 0.f, 0.f, 0.f);
            if (grow < NN) v = X4[(size_t)grow * 32 + c4];
            __half2 a = __floats2half2_rn(v.x, v.y);
            __half2 b = __floats2half2_rn(v.z, v.w);
            uint2 pk;
            pk.x = *(unsigned int*)&a;
            pk.y = *(unsigned int*)&b;
            *(uint2*)&Al[r * LPAD + c4 * 4] = pk;
        }
    }
    __syncthreads();

    const int wave = tid >> 6;
    const int lane = tid & 63;
    const int m    = lane & 15;
    const int quad = lane >> 4;

    f32x4 acc[8];
    #pragma unroll
    for (int t = 0; t < 8; ++t) acc[t] = (f32x4){0.f, 0.f, 0.f, 0.f};

    #pragma unroll
    for (int kk = 0; kk < DD; kk += 32) {
        half8_t a = *(const half8_t*)&Al[(wave * 16 + m) * LPAD + kk + quad * 8];
        #pragma unroll
        for (int t = 0; t < 8; ++t) {
            half8_t b = *(const half8_t*)&Wl[(t * 16 + m) * LPAD + kk + quad * 8];
            acc[t] = __builtin_amdgcn_mfma_f32_16x16x32_f16(a, b, acc[t], 0, 0, 0);
        }
    }

    __syncthreads();

    float4 dv = *(const float4*)&dinv[row0 + wave * 16 + quad * 4];

    #pragma unroll
    for (int t = 0; t < 8; ++t) {
        #pragma unroll
        for (int r = 0; r < 4; ++r) {
            int row_l = wave * 16 + quad * 4 + r;
            int c     = t * 16 + m;
            float val = acc[t][r] * ((const float*)&dv)[r];
            Al[row_l * LPAD + c] = __float2half(val);
        }
    }
    __syncthreads();

    {
        #pragma unroll
        for (int j = 0; j < 4; ++j) {
            int u = tid + j * 256;
            int r = u >> 4, c16 = u & 15;
            int ch = c16 >> 3, wi = c16 & 7;
            int grow = row0 + r;
            if (grow < NN) {
                uint4 v = *(const uint4*)&Al[r * LPAD + c16 * 8];
                *(uint4*)(Gc + (size_t)ch * SLAB2 + (size_t)grow * 64 + wi * 8) = v;
            }
        }
    }
}

// ---------------- MFMA GEMM (layer 2): half chunk-slab input ----------------

__global__ __launch_bounds__(256) void k_gemm_h(const __half* __restrict__ Xc, const __half* __restrict__ WT,
                                                const float* __restrict__ dinv, __half* __restrict__ Gc) {
    __shared__ __half Wl[DD * LPAD];
    __shared__ __half Al[64 * LPAD];

    const int tid  = threadIdx.x;
    const int row0 = blockIdx.x * 64;

    {
        const uint4* WTg = (const uint4*)WT;
        #pragma unroll
        for (int j = 0; j < 8; ++j) {
            int u = tid + j * 256;
            int n = u >> 4, koff = (u & 15) * 8;
            uint4 v = WTg[u];
            *(uint4*)&Wl[n * LPAD + koff] = v;
        }
    }
    {
        #pragma unroll
        for (int j = 0; j < 4; ++j) {
            int u = tid + j * 256;
            int r = u >> 4, c16 = u & 15;
            int ch = c16 >> 3, wi = c16 & 7;
            int grow = row0 + r;
            uint4 v;
            if (grow < NN) v = *(const uint4*)(Xc + (size_t)ch * SLAB2 + (size_t)grow * 64 + wi * 8);
            else { v.x = 0; v.y = 0; v.z = 0; v.w = 0; }
            *(uint4*)&Al[r * LPAD + c16 * 8] = v;
        }
    }
    __syncthreads();

    const int wave = tid >> 6;
    const int lane = tid & 63;
    const int m    = lane & 15;
    const int quad = lane >> 4;

    f32x4 acc[8];
    #pragma unroll
    for (int t = 0; t < 8; ++t) acc[t] = (f32x4){0.f, 0.f, 0.f, 0.f};

    #pragma unroll
    for (int kk = 0; kk < DD; kk += 32) {
        half8_t a = *(const half8_t*)&Al[(wave * 16 + m) * LPAD + kk + quad * 8];
        #pragma unroll
        for (int t = 0; t < 8; ++t) {
            half8_t b = *(const half8_t*)&Wl[(t * 16 + m) * LPAD + kk + quad * 8];
            acc[t] = __builtin_amdgcn_mfma_f32_16x16x32_f16(a, b, acc[t], 0, 0, 0);
        }
    }

    __syncthreads();

    float4 dv = *(const float4*)&dinv[row0 + wave * 16 + quad * 4];

    #pragma unroll
    for (int t = 0; t < 8; ++t) {
        #pragma unroll
        for (int r = 0; r < 4; ++r) {
            int row_l = wave * 16 + quad * 4 + r;
            int c     = t * 16 + m;
            float val = acc[t][r] * ((const float*)&dv)[r];
            Al[row_l * LPAD + c] = __float2half(val);
        }
    }
    __syncthreads();

    {
        #pragma unroll
        for (int j = 0; j < 4; ++j) {
            int u = tid + j * 256;
            int r = u >> 4, c16 = u & 15;
            int ch = c16 >> 3, wi = c16 & 7;
            int grow = row0 + r;
            if (grow < NN) {
                uint4 v = *(const uint4*)&Al[r * LPAD + c16 * 8];
                *(uint4*)(Gc + (size_t)ch * SLAB2 + (size_t)grow * 64 + wi * 8) = v;
            }
        }
    }
}

// ---------------- Aggregation: 16-lane group per node, 64-feat chunks, 8-wide MLP gather ----------------

__device__ inline float4 h4_to_f4(uint2 r) {
    __half2 a = *(__half2*)&r.x;
    __half2 b = *(__half2*)&r.y;
    float2 lo = __half22float2(a), hi = __half22float2(b);
    return make_float4(lo.x, lo.y, hi.x, hi.y);
}

__device__ inline uint2 f4_to_h4(float4 v) {
    __half2 a = __floats2half2_rn(v.x, v.y);
    __half2 b = __floats2half2_rn(v.z, v.w);
    uint2 r;
    r.x = *(unsigned int*)&a;
    r.y = *(unsigned int*)&b;
    return r;
}

__device__ inline float4 gather_grp64(const __half* __restrict__ slab, int node, int fl,
                                      const unsigned short* __restrict__ col, int beg, int end) {
    const __half* base = slab + fl * 4;   // lane's 8-B column within each 128-B row
    float4 accA = h4_to_f4(*(const uint2*)(base + (size_t)node * 64));  // self term
    float4 accB = make_float4(0.f, 0.f, 0.f, 0.f);
    int p = beg;
    // 8-wide main step: 8 independent loads in flight
    for (; p + 7 < end; p += 8) {
        int s0 = col[p],     s1 = col[p + 1], s2 = col[p + 2], s3 = col[p + 3];
        int s4 = col[p + 4], s5 = col[p + 5], s6 = col[p + 6], s7 = col[p + 7];
        float4 v0 = h4_to_f4(*(const uint2*)(base + (size_t)s0 * 64));
        float4 v1 = h4_to_f4(*(const uint2*)(base + (size_t)s1 * 64));
        float4 v2 = h4_to_f4(*(const uint2*)(base + (size_t)s2 * 64));
        float4 v3 = h4_to_f4(*(const uint2*)(base + (size_t)s3 * 64));
        float4 v4 = h4_to_f4(*(const uint2*)(base + (size_t)s4 * 64));
        float4 v5 = h4_to_f4(*(const uint2*)(base + (size_t)s5 * 64));
        float4 v6 = h4_to_f4(*(const uint2*)(base + (size_t)s6 * 64));
        float4 v7 = h4_to_f4(*(const uint2*)(base + (size_t)s7 * 64));
        accA.x += (v0.x + v1.x) + (v4.x + v5.x);
        accA.y += (v0.y + v1.y) + (v4.y + v5.y);
        accA.z += (v0.z + v1.z) + (v4.z + v5.z);
        accA.w += (v0.w + v1.w) + (v4.w + v5.w);
        accB.x += (v2.x + v3.x) + (v6.x + v7.x);
        accB.y += (v2.y + v3.y) + (v6.y + v7.y);
        accB.z += (v2.z + v3.z) + (v6.z + v7.z);
        accB.w += (v2.w + v3.w) + (v6.w + v7.w);
    }
    // 4-wide mid step
    if (p + 3 < end) {
        int s0 = col[p], s1 = col[p + 1], s2 = col[p + 2], s3 = col[p + 3];
        float4 v0 = h4_to_f4(*(const uint2*)(base + (size_t)s0 * 64));
        float4 v1 = h4_to_f4(*(const uint2*)(base + (size_t)s1 * 64));
        float4 v2 = h4_to_f4(*(const uint2*)(base + (size_t)s2 * 64));
        float4 v3 = h4_to_f4(*(const uint2*)(base + (size_t)s3 * 64));
        accA.x += v0.x + v1.x; accA.y += v0.y + v1.y; accA.z += v0.z + v1.z; accA.w += v0.w + v1.w;
        accB.x += v2.x + v3.x; accB.y += v2.y + v3.y; accB.z += v2.z + v3.z; accB.w += v2.w + v3.w;
        p += 4;
    }
    // scalar tail (<= 3)
    for (; p < end; ++p) {
        int s0 = col[p];
        float4 v0 = h4_to_f4(*(const uint2*)(base + (size_t)s0 * 64));
        accA.x += v0.x; accA.y += v0.y; accA.z += v0.z; accA.w += v0.w;
    }
    accA.x += accB.x; accA.y += accB.y; accA.z += accB.z; accA.w += accB.w;
    return accA;
}

__global__ __launch_bounds__(256) void k_aggregate_c(const __half* __restrict__ G, const float* __restrict__ dinv,
                                                     const int* __restrict__ row_ptr, const unsigned short* __restrict__ col,
                                                     const float* __restrict__ bias, __half* __restrict__ H) {
    const int bx    = blockIdx.x;
    const int slot  = bx & 7;
    const int chunk = slot >> 2;
    const int nb    = (bx >> 3) * 4 + (slot & 3);     // node-block (16 nodes), 0..3127
    const int g     = threadIdx.x >> 4;               // 0..15
    const int fl    = threadIdx.x & 15;
    const int node  = nb * 16 + g;
    if (node >= NN) return;

    const __half* slab = G + (size_t)chunk * SLAB2;
    int beg = row_ptr[node];
    int end = row_ptr[node + 1];
    float4 acc = gather_grp64(slab, node, fl, col, beg, end);

    float di = dinv[node];
    float4 bv = *(const float4*)(bias + chunk * 64 + fl * 4);
    float4 hv;
    hv.x = fmaxf(fmaf(di, acc.x, bv.x), 0.f);
    hv.y = fmaxf(fmaf(di, acc.y, bv.y), 0.f);
    hv.z = fmaxf(fmaf(di, acc.z, bv.z), 0.f);
    hv.w = fmaxf(fmaf(di, acc.w, bv.w), 0.f);
    *(uint2*)(H + (size_t)chunk * SLAB2 + (size_t)node * 64 + fl * 4) = f4_to_h4(hv);
}

__global__ __launch_bounds__(256) void k_aggregate_heads_c(const __half* __restrict__ G, const float* __restrict__ dinv,
                                                           const int* __restrict__ row_ptr, const unsigned short* __restrict__ col,
                                                           const float* __restrict__ bias,
                                                           const float* __restrict__ Wt, const float* __restrict__ bt,
                                                           const float* __restrict__ We, const float* __restrict__ be,
                                                           float* __restrict__ out) {
    const int bx    = blockIdx.x;
    const int slot  = bx & 7;
    const int chunk = slot >> 2;
    const int nb    = (bx >> 3) * 4 + (slot & 3);
    const int g     = threadIdx.x >> 4;
    const int fl    = threadIdx.x & 15;
    const int node  = nb * 16 + g;
    if (node >= NN) return;

    const __half* slab = G + (size_t)chunk * SLAB2;
    int beg = row_ptr[node];
    int end = row_ptr[node + 1];
    float4 acc = gather_grp64(slab, node, fl, col, beg, end);

    float di = dinv[node];
    float4 bv = *(const float4*)(bias + chunk * 64 + fl * 4);
    float hx = fmaxf(fmaf(di, acc.x, bv.x), 0.f);
    float hy = fmaxf(fmaf(di, acc.y, bv.y), 0.f);
    float hz = fmaxf(fmaf(di, acc.z, bv.z), 0.f);
    float hw = fmaxf(fmaf(di, acc.w, bv.w), 0.f);

    float4 wt = *(const float4*)(Wt + chunk * 64 + fl * 4);
    float4 we = *(const float4*)(We + chunk * 64 + fl * 4);
    float t  = hx * wt.x + hy * wt.y + hz * wt.z + hw * wt.w;
    float ev = hx * we.x + hy * we.y + hz * we.z + hw * we.w;
    #pragma unroll
    for (int o = 1; o < 16; o <<= 1) {
        t  += __shfl_xor(t, o, 64);
        ev += __shfl_xor(ev, o, 64);
    }
    if (fl == 0) {
        if (chunk == 0) { t += bt[0]; ev += be[0]; }
        atomicAdd(&out[node], t);
        atomicAdd(&out[NN + node], ev);
    }
}

// ---------------- launch ----------------

extern "C" void kernel_launch(void* const* d_in, const int* in_sizes, int n_in,
                              void* d_out, int out_size, void* d_ws, size_t ws_size,
                              hipStream_t stream) {
    const float* x  = (const float*)d_in[0];
    const int*   ei = (const int*)d_in[1];
    const float* W1 = (const float*)d_in[2];
    const float* b1 = (const float*)d_in[3];
    const float* W2 = (const float*)d_in[4];
    const float* b2 = (const float*)d_in[5];
    const float* Wt = (const float*)d_in[6];
    const float* bt = (const float*)d_in[7];
    const float* We = (const float*)d_in[8];
    const float* be = (const float*)d_in[9];
    float* out = (float*)d_out;

    const int* srcI = ei;
    const int* dstI = ei + NE;

    char* w = (char*)d_ws;
    __half*         Gh    = (__half*)w;         w += (size_t)NN * DD * sizeof(__half);        // 12.8 MB (2 slabs)
    __half*         H1h   = (__half*)w;         w += (size_t)NN * DD * sizeof(__half);        // 12.8 MB (2 slabs)
    __half*         WT1   = (__half*)w;         w += (size_t)DD * DD * sizeof(__half);
    __half*         WT2   = (__half*)w;         w += (size_t)DD * DD * sizeof(__half);
    unsigned int*   ebuf  = (unsigned int*)w;   w += (size_t)NB * CAP * sizeof(unsigned int); // 4.15 MB
    unsigned short* col   = (unsigned short*)w; w += (size_t)NE * sizeof(unsigned short);     // 1.6 MB
    float*          dinv  = (float*)w;          w += (size_t)(NN + 64) * sizeof(float);       // padded
    int*            rowp  = (int*)w;            w += (size_t)(NN + 1) * sizeof(int);
    int*            bcnt  = (int*)w;            w += (size_t)NB * sizeof(int);

    const int SETUP_B = A_BLOCKS + 2;            // 198
    const int NBLK    = (NN + 15) / 16;          // 3125 node-blocks per chunk
    const int AGG_B   = ((NBLK + 3) / 4) * 8;    // 6256: 2 chunks x 4 slots x 782

    hipMemsetAsync(bcnt, 0, (size_t)NB * sizeof(int), stream);

    hipLaunchKernelGGL(k_setup,     dim3(SETUP_B), dim3(256), 0, stream,
                       srcI, dstI, bcnt, ebuf, W1, W2, WT1, WT2);
    hipLaunchKernelGGL(k_build_csr, dim3(NB),      dim3(512), 0, stream, ebuf, bcnt, rowp, dinv, col);

    // layer 1 (gemm1 reads fp32 x directly; tail blocks zero `out`)
    hipLaunchKernelGGL(k_gemm_x,      dim3(GEMM_B + ZERO_B), dim3(256), 0, stream, x, WT1, dinv, Gh, out, out_size);
    hipLaunchKernelGGL(k_aggregate_c, dim3(AGG_B),           dim3(256), 0, stream, Gh, dinv, rowp, col, b1, H1h);

    // layer 2 + heads
    hipLaunchKernelGGL(k_gemm_h,            dim3(GEMM_B), dim3(256), 0, stream, H1h, WT2, dinv, Gh);
    hipLaunchKernelGGL(k_aggregate_heads_c, dim3(AGG_B),  dim3(256), 0, stream, Gh, dinv, rowp, col, b2,
                       Wt, bt, We, be, out);
}

// Round 12
// 183.787 us; speedup vs baseline: 1.1672x; 1.1017x over previous
//
#include <hip/hip_runtime.h>
#include <hip/hip_fp16.h>
#include <math.h>

#define NN 50000
#define NNP 50048        // padded row count (includes zero rows >= NN)
#define NE 800000
#define DD 128

#define NB  196      // buckets of 256 nodes (dst >> 8)
#define CAP 5300     // raw per-bucket segment capacity in ebuf
#define CAPP 6400    // padded per-bucket col capacity (raw max ~4470 + pad <=1792)
#define EPB 4096     // edges per phase-A block
#define A_BLOCKS 196 // ceil(NE/EPB)

#define SLAB2 (NNP * 64)  // halves per 64-feature chunk slab; 2 chunks

typedef _Float16 half8_t __attribute__((ext_vector_type(8)));
typedef float f32x4 __attribute__((ext_vector_type(4)));

// ---------------- fused setup: phaseA edge binning || W transpose ----------------
// bcnt must be zeroed before launch.

__global__ __launch_bounds__(256) void k_setup(const int* __restrict__ src, const int* __restrict__ dst,
                                               int* __restrict__ bcnt, unsigned int* __restrict__ ebuf,
                                               const float* __restrict__ W1, const float* __restrict__ W2,
                                               __half* __restrict__ WT1, __half* __restrict__ WT2) {
    const int blk = blockIdx.x;
    const int tid = threadIdx.x;

    if (blk < A_BLOCKS) {
        __shared__ int hist[256];
        __shared__ int scanbuf[256];
        __shared__ int gbase[256];
        __shared__ unsigned int stage[EPB];
        __shared__ int tgt[EPB];

        const int e0 = blk * EPB;
        int nE = NE - e0; if (nE > EPB) nE = EPB;

        hist[tid] = 0;
        __syncthreads();

        unsigned int pk[16];
        unsigned int br[16];   // bucket(8b) | rank<<8
        #pragma unroll
        for (int j = 0; j < 16; ++j) {
            int idx = tid + j * 256;
            if (idx < nE) {
                int e = e0 + idx;
                int s = src[e], d = dst[e];
                int b = d >> 8;
                int r = atomicAdd(&hist[b], 1);
                pk[j] = (unsigned int)s | ((unsigned int)(d & 255) << 16);
                br[j] = (unsigned int)b | ((unsigned int)r << 8);
            }
        }
        __syncthreads();
        int v = hist[tid];
        scanbuf[tid] = v;
        __syncthreads();
        for (int o = 1; o < 256; o <<= 1) {
            int t2 = (tid >= o) ? scanbuf[tid - o] : 0;
            __syncthreads();
            scanbuf[tid] += t2;
            __syncthreads();
        }
        int base_excl = scanbuf[tid] - v;
        if (tid < NB && v > 0) gbase[tid] = tid * CAP + atomicAdd(&bcnt[tid], v);
        hist[tid] = base_excl;
        __syncthreads();

        #pragma unroll
        for (int j = 0; j < 16; ++j) {
            int idx = tid + j * 256;
            if (idx < nE) {
                int b = br[j] & 255;
                int r = (int)(br[j] >> 8);
                int pos = hist[b] + r;
                stage[pos] = pk[j];
                tgt[pos]   = gbase[b] + r;
            }
        }
        __syncthreads();
        #pragma unroll
        for (int j = 0; j < 16; ++j) {
            int idx = tid + j * 256;
            if (idx < nE) ebuf[tgt[idx]] = stage[idx];
        }
    } else {
        const float* W  = (blk == A_BLOCKS) ? W1 : W2;
        __half*      WT = (blk == A_BLOCKS) ? WT1 : WT2;
        int n = tid >> 1;
        int k0 = (tid & 1) * 64;
        #pragma unroll 8
        for (int j = 0; j < 64; ++j) {
            int k = k0 + j;
            WT[n * DD + k] = __float2half(W[k * DD + n]);
        }
    }
}

// ---------------- Phase B: per-bucket CSR with 8-padded node lists ----------------
// Each node's list padded to multiple of 8 with dummy index NN (a zero row).
// Bucket b owns col region [b*CAPP, b*CAPP + padded_size). rowbeg/rowend per node.

__global__ __launch_bounds__(512) void k_build_csr(const unsigned int* __restrict__ ebuf,
                                                   const int* __restrict__ bcnt,
                                                   int* __restrict__ rowbeg, int* __restrict__ rowend,
                                                   float* __restrict__ dinv,
                                                   unsigned short* __restrict__ col) {
    __shared__ int cnt[256];
    __shared__ int scanb[256];
    __shared__ unsigned short stage[CAPP];

    const int b   = blockIdx.x;
    const int tid = threadIdx.x;
    const int seg0 = b * CAP;
    const int sb   = bcnt[b];
    const int n0   = b << 8;
    int nb = NN - n0; if (nb > 256) nb = 256;

    // per-node raw histogram
    if (tid < 256) cnt[tid] = 0;
    __syncthreads();
    for (int p = tid; p < sb; p += 512) {
        unsigned int e = ebuf[seg0 + p];
        atomicAdd(&cnt[(e >> 16) & 255], 1);
    }
    __syncthreads();
    int v  = (tid < 256) ? cnt[tid] : 0;
    int pv = (v + 7) & ~7;                 // padded length
    if (tid < 256) scanb[tid] = pv;
    __syncthreads();
    for (int o = 1; o < 256; o <<= 1) {
        int t = 0;
        if (tid < 256 && tid >= o) t = scanb[tid - o];
        __syncthreads();
        if (tid < 256) scanb[tid] += t;
        __syncthreads();
    }
    int exclp = (tid < 256) ? (scanb[tid] - pv) : 0;   // padded exclusive prefix
    if (tid < nb) {
        rowbeg[n0 + tid] = b * CAPP + exclp;
        rowend[n0 + tid] = b * CAPP + exclp + pv;
        dinv[n0 + tid] = rsqrtf(1.0f + (float)v);
    }
    if (tid < 256) cnt[tid] = exclp;       // cursor at padded base
    __syncthreads();
    for (int p = tid; p < sb; p += 512) {
        unsigned int e = ebuf[seg0 + p];
        int pos = atomicAdd(&cnt[(e >> 16) & 255], 1);
        stage[pos] = (unsigned short)(e & 0xFFFFu);
    }
    __syncthreads();
    // pad fill with dummy index NN
    if (tid < nb) {
        for (int k = exclp + v; k < exclp + pv; ++k) stage[k] = (unsigned short)NN;
    }
    __syncthreads();
    const int sbp = scanb[255];            // total padded size of this bucket
    for (int p = tid; p < sbp; p += 512) {
        col[b * CAPP + p] = stage[p];
    }
}

// ---------------- MFMA GEMM (layer 1): fp32 input, converts during staging; zero-tail ----------------
// Stores ALL 64 rows of its tile (rows >= NN get exact zeros -> dummy row NN is zero).

#define LPAD 136
#define GEMM_B 782          // ceil(NNP/64) == ceil(NN/64)
#define ZERO_B 98           // ceil(100000 floats / (256*4))

__global__ __launch_bounds__(256) void k_gemm_x(const float* __restrict__ X, const __half* __restrict__ WT,
                                                const float* __restrict__ dinv, __half* __restrict__ Gc,
                                                float* __restrict__ zbuf, int zcount) {
    const int tid = threadIdx.x;

    if (blockIdx.x >= GEMM_B) {
        int idx = (blockIdx.x - GEMM_B) * 256 + tid;   // float4 index
        if (idx * 4 + 3 < zcount) ((float4*)zbuf)[idx] = make_float4(0.f, 0.f, 0.f, 0.f);
        else {
            for (int k = idx * 4; k < zcount; ++k) zbuf[k] = 0.f;
        }
        return;
    }

    __shared__ __half Wl[DD * LPAD];
    __shared__ __half Al[64 * LPAD];

    const int row0 = blockIdx.x * 64;

    {
        const uint4* WTg = (const uint4*)WT;
        #pragma unroll
        for (int j = 0; j < 8; ++j) {
            int u = tid + j * 256;
            int n = u >> 4, koff = (u & 15) * 8;
            uint4 v = WTg[u];
            *(uint4*)&Wl[n * LPAD + koff] = v;
        }
    }
    {
        const float4* X4 = (const float4*)X;
        #pragma unroll
        for (int j = 0; j < 8; ++j) {
            int u = tid + j * 256;             // 0..2047
            int r = u >> 5, c4 = u & 31;
            int grow = row0 + r;
            float4 v = make_float4(0.f, 0.f, 0.f, 0.f);
            if (grow < NN) v = X4[(size_t)grow * 32 + c4];
            __half2 a = __floats2half2_rn(v.x, v.y);
            __half2 b = __floats2half2_rn(v.z, v.w);
            uint2 pk;
            pk.x = *(unsigned int*)&a;
            pk.y = *(unsigned int*)&b;
            *(uint2*)&Al[r * LPAD + c4 * 4] = pk;
        }
    }
    __syncthreads();

    const int wave = tid >> 6;
    const int lane = tid & 63;
    const int m    = lane & 15;
    const int quad = lane >> 4;

    f32x4 acc[8];
    #pragma unroll
    for (int t = 0; t < 8; ++t) acc[t] = (f32x4){0.f, 0.f, 0.f, 0.f};

    #pragma unroll
    for (int kk = 0; kk < DD; kk += 32) {
        half8_t a = *(const half8_t*)&Al[(wave * 16 + m) * LPAD + kk + quad * 8];
        #pragma unroll
        for (int t = 0; t < 8; ++t) {
            half8_t b = *(const half8_t*)&Wl[(t * 16 + m) * LPAD + kk + quad * 8];
            acc[t] = __builtin_amdgcn_mfma_f32_16x16x32_f16(a, b, acc[t], 0, 0, 0);
        }
    }

    __syncthreads();

    float4 dv = *(const float4*)&dinv[row0 + wave * 16 + quad * 4];

    #pragma unroll
    for (int t = 0; t < 8; ++t) {
        #pragma unroll
        for (int r = 0; r < 4; ++r) {
            int row_l = wave * 16 + quad * 4 + r;
            int c     = t * 16 + m;
            float val = acc[t][r] * ((const float*)&dv)[r];   // rows >= NN: acc==0 -> 0
            Al[row_l * LPAD + c] = __float2half(val);
        }
    }
    __syncthreads();

    {
        #pragma unroll
        for (int j = 0; j < 4; ++j) {
            int u = tid + j * 256;
            int r = u >> 4, c16 = u & 15;
            int ch = c16 >> 3, wi = c16 & 7;
            int grow = row0 + r;                // always < NNP
            uint4 v = *(const uint4*)&Al[r * LPAD + c16 * 8];
            *(uint4*)(Gc + (size_t)ch * SLAB2 + (size_t)grow * 64 + wi * 8) = v;
        }
    }
}

// ---------------- MFMA GEMM (layer 2): half chunk-slab input ----------------

__global__ __launch_bounds__(256) void k_gemm_h(const __half* __restrict__ Xc, const __half* __restrict__ WT,
                                                const float* __restrict__ dinv, __half* __restrict__ Gc) {
    __shared__ __half Wl[DD * LPAD];
    __shared__ __half Al[64 * LPAD];

    const int tid  = threadIdx.x;
    const int row0 = blockIdx.x * 64;

    {
        const uint4* WTg = (const uint4*)WT;
        #pragma unroll
        for (int j = 0; j < 8; ++j) {
            int u = tid + j * 256;
            int n = u >> 4, koff = (u & 15) * 8;
            uint4 v = WTg[u];
            *(uint4*)&Wl[n * LPAD + koff] = v;
        }
    }
    {
        #pragma unroll
        for (int j = 0; j < 4; ++j) {
            int u = tid + j * 256;
            int r = u >> 4, c16 = u & 15;
            int ch = c16 >> 3, wi = c16 & 7;
            int grow = row0 + r;
            uint4 v;
            if (grow < NN) v = *(const uint4*)(Xc + (size_t)ch * SLAB2 + (size_t)grow * 64 + wi * 8);
            else { v.x = 0; v.y = 0; v.z = 0; v.w = 0; }
            *(uint4*)&Al[r * LPAD + c16 * 8] = v;
        }
    }
    __syncthreads();

    const int wave = tid >> 6;
    const int lane = tid & 63;
    const int m    = lane & 15;
    const int quad = lane >> 4;

    f32x4 acc[8];
    #pragma unroll
    for (int t = 0; t < 8; ++t) acc[t] = (f32x4){0.f, 0.f, 0.f, 0.f};

    #pragma unroll
    for (int kk = 0; kk < DD; kk += 32) {
        half8_t a = *(const half8_t*)&Al[(wave * 16 + m) * LPAD + kk + quad * 8];
        #pragma unroll
        for (int t = 0; t < 8; ++t) {
            half8_t b = *(const half8_t*)&Wl[(t * 16 + m) * LPAD + kk + quad * 8];
            acc[t] = __builtin_amdgcn_mfma_f32_16x16x32_f16(a, b, acc[t], 0, 0, 0);
        }
    }

    __syncthreads();

    float4 dv = *(const float4*)&dinv[row0 + wave * 16 + quad * 4];

    #pragma unroll
    for (int t = 0; t < 8; ++t) {
        #pragma unroll
        for (int r = 0; r < 4; ++r) {
            int row_l = wave * 16 + quad * 4 + r;
            int c     = t * 16 + m;
            float val = acc[t][r] * ((const float*)&dv)[r];
            Al[row_l * LPAD + c] = __float2half(val);
        }
    }
    __syncthreads();

    {
        #pragma unroll
        for (int j = 0; j < 4; ++j) {
            int u = tid + j * 256;
            int r = u >> 4, c16 = u & 15;
            int ch = c16 >> 3, wi = c16 & 7;
            int grow = row0 + r;                // always < NNP
            uint4 v = *(const uint4*)&Al[r * LPAD + c16 * 8];
            *(uint4*)(Gc + (size_t)ch * SLAB2 + (size_t)grow * 64 + wi * 8) = v;
        }
    }
}

// ---------------- Aggregation: 16-lane group per node, padded lists, vector col ----------------
// Inner loop: 1 uint4 col load (8 packed indices) + 8 feature loads. No tails, no branches.

__device__ inline float4 h4_to_f4(uint2 r) {
    __half2 a = *(__half2*)&r.x;
    __half2 b = *(__half2*)&r.y;
    float2 lo = __half22float2(a), hi = __half22float2(b);
    return make_float4(lo.x, lo.y, hi.x, hi.y);
}

__device__ inline uint2 f4_to_h4(float4 v) {
    __half2 a = __floats2half2_rn(v.x, v.y);
    __half2 b = __floats2half2_rn(v.z, v.w);
    uint2 r;
    r.x = *(unsigned int*)&a;
    r.y = *(unsigned int*)&b;
    return r;
}

__device__ inline float4 gather_grp64(const __half* __restrict__ slab, int node, int fl,
                                      const unsigned short* __restrict__ col, int beg, int end) {
    const __half* base = slab + fl * 4;   // lane's 8-B column within each 128-B row
    float4 accA = h4_to_f4(*(const uint2*)(base + (size_t)node * 64));  // self term
    float4 accB = make_float4(0.f, 0.f, 0.f, 0.f);
    for (int p = beg; p < end; p += 8) {
        uint4 c8 = *(const uint4*)(col + p);           // 8 packed ushort indices, 16-B aligned
        int s0 = c8.x & 0xFFFF, s1 = c8.x >> 16;
        int s2 = c8.y & 0xFFFF, s3 = c8.y >> 16;
        int s4 = c8.z & 0xFFFF, s5 = c8.z >> 16;
        int s6 = c8.w & 0xFFFF, s7 = c8.w >> 16;
        float4 v0 = h4_to_f4(*(const uint2*)(base + (size_t)s0 * 64));
        float4 v1 = h4_to_f4(*(const uint2*)(base + (size_t)s1 * 64));
        float4 v2 = h4_to_f4(*(const uint2*)(base + (size_t)s2 * 64));
        float4 v3 = h4_to_f4(*(const uint2*)(base + (size_t)s3 * 64));
        float4 v4 = h4_to_f4(*(const uint2*)(base + (size_t)s4 * 64));
        float4 v5 = h4_to_f4(*(const uint2*)(base + (size_t)s5 * 64));
        float4 v6 = h4_to_f4(*(const uint2*)(base + (size_t)s6 * 64));
        float4 v7 = h4_to_f4(*(const uint2*)(base + (size_t)s7 * 64));
        accA.x += (v0.x + v1.x) + (v4.x + v5.x);
        accA.y += (v0.y + v1.y) + (v4.y + v5.y);
        accA.z += (v0.z + v1.z) + (v4.z + v5.z);
        accA.w += (v0.w + v1.w) + (v4.w + v5.w);
        accB.x += (v2.x + v3.x) + (v6.x + v7.x);
        accB.y += (v2.y + v3.y) + (v6.y + v7.y);
        accB.z += (v2.z + v3.z) + (v6.z + v7.z);
        accB.w += (v2.w + v3.w) + (v6.w + v7.w);
    }
    accA.x += accB.x; accA.y += accB.y; accA.z += accB.z; accA.w += accB.w;
    return accA;
}

__global__ __launch_bounds__(256) void k_aggregate_c(const __half* __restrict__ G, const float* __restrict__ dinv,
                                                     const int* __restrict__ rowbeg, const int* __restrict__ rowend,
                                                     const unsigned short* __restrict__ col,
                                                     const float* __restrict__ bias, __half* __restrict__ H) {
    const int bx    = blockIdx.x;
    const int slot  = bx & 7;
    const int chunk = slot >> 2;
    const int nb    = (bx >> 3) * 4 + (slot & 3);     // node-block (16 nodes), 0..3127
    const int g     = threadIdx.x >> 4;               // 0..15
    const int fl    = threadIdx.x & 15;
    const int node  = nb * 16 + g;
    if (node >= NN) return;

    const __half* slab = G + (size_t)chunk * SLAB2;
    int beg = rowbeg[node];
    int end = rowend[node];
    float4 acc = gather_grp64(slab, node, fl, col, beg, end);

    float di = dinv[node];
    float4 bv = *(const float4*)(bias + chunk * 64 + fl * 4);
    float4 hv;
    hv.x = fmaxf(fmaf(di, acc.x, bv.x), 0.f);
    hv.y = fmaxf(fmaf(di, acc.y, bv.y), 0.f);
    hv.z = fmaxf(fmaf(di, acc.z, bv.z), 0.f);
    hv.w = fmaxf(fmaf(di, acc.w, bv.w), 0.f);
    *(uint2*)(H + (size_t)chunk * SLAB2 + (size_t)node * 64 + fl * 4) = f4_to_h4(hv);
}

__global__ __launch_bounds__(256) void k_aggregate_heads_c(const __half* __restrict__ G, const float* __restrict__ dinv,
                                                           const int* __restrict__ rowbeg, const int* __restrict__ rowend,
                                                           const unsigned short* __restrict__ col,
                                                           const float* __restrict__ bias,
                                                           const float* __restrict__ Wt, const float* __restrict__ bt,
                                                           const float* __restrict__ We, const float* __restrict__ be,
                                                           float* __restrict__ out) {
    const int bx    = blockIdx.x;
    const int slot  = bx & 7;
    const int chunk = slot >> 2;
    const int nb    = (bx >> 3) * 4 + (slot & 3);
    const int g     = threadIdx.x >> 4;
    const int fl    = threadIdx.x & 15;
    const int node  = nb * 16 + g;
    if (node >= NN) return;

    const __half* slab = G + (size_t)chunk * SLAB2;
    int beg = rowbeg[node];
    int end = rowend[node];
    float4 acc = gather_grp64(slab, node, fl, col, beg, end);

    float di = dinv[node];
    float4 bv = *(const float4*)(bias + chunk * 64 + fl * 4);
    float hx = fmaxf(fmaf(di, acc.x, bv.x), 0.f);
    float hy = fmaxf(fmaf(di, acc.y, bv.y), 0.f);
    float hz = fmaxf(fmaf(di, acc.z, bv.z), 0.f);
    float hw = fmaxf(fmaf(di, acc.w, bv.w), 0.f);

    float4 wt = *(const float4*)(Wt + chunk * 64 + fl * 4);
    float4 we = *(const float4*)(We + chunk * 64 + fl * 4);
    float t  = hx * wt.x + hy * wt.y + hz * wt.z + hw * wt.w;
    float ev = hx * we.x + hy * we.y + hz * we.z + hw * we.w;
    #pragma unroll
    for (int o = 1; o < 16; o <<= 1) {
        t  += __shfl_xor(t, o, 64);
        ev += __shfl_xor(ev, o, 64);
    }
    if (fl == 0) {
        if (chunk == 0) { t += bt[0]; ev += be[0]; }
        atomicAdd(&out[node], t);
        atomicAdd(&out[NN + node], ev);
    }
}

// ---------------- launch ----------------

extern "C" void kernel_launch(void* const* d_in, const int* in_sizes, int n_in,
                              void* d_out, int out_size, void* d_ws, size_t ws_size,
                              hipStream_t stream) {
    const float* x  = (const float*)d_in[0];
    const int*   ei = (const int*)d_in[1];
    const float* W1 = (const float*)d_in[2];
    const float* b1 = (const float*)d_in[3];
    const float* W2 = (const float*)d_in[4];
    const float* b2 = (const float*)d_in[5];
    const float* Wt = (const float*)d_in[6];
    const float* bt = (const float*)d_in[7];
    const float* We = (const float*)d_in[8];
    const float* be = (const float*)d_in[9];
    float* out = (float*)d_out;

    const int* srcI = ei;
    const int* dstI = ei + NE;

    char* w = (char*)d_ws;
    __half*         Gh    = (__half*)w;         w += (size_t)2 * SLAB2 * sizeof(__half);       // 12.8 MB
    __half*         H1h   = (__half*)w;         w += (size_t)2 * SLAB2 * sizeof(__half);       // 12.8 MB
    __half*         WT1   = (__half*)w;         w += (size_t)DD * DD * sizeof(__half);
    __half*         WT2   = (__half*)w;         w += (size_t)DD * DD * sizeof(__half);
    unsigned int*   ebuf  = (unsigned int*)w;   w += (size_t)NB * CAP * sizeof(unsigned int);  // 4.15 MB
    unsigned short* col   = (unsigned short*)w; w += (size_t)NB * CAPP * sizeof(unsigned short); // 2.5 MB
    float*          dinv  = (float*)w;          w += (size_t)(NN + 64) * sizeof(float);        // padded
    int*            rowbeg= (int*)w;            w += (size_t)NN * sizeof(int);
    int*            rowend= (int*)w;            w += (size_t)NN * sizeof(int);
    int*            bcnt  = (int*)w;            w += (size_t)NB * sizeof(int);

    const int SETUP_B = A_BLOCKS + 2;            // 198
    const int NBLK    = (NN + 15) / 16;          // 3125 node-blocks per chunk
    const int AGG_B   = ((NBLK + 3) / 4) * 8;    // 6256: 2 chunks x 4 slots x 782

    hipMemsetAsync(bcnt, 0, (size_t)NB * sizeof(int), stream);

    hipLaunchKernelGGL(k_setup,     dim3(SETUP_B), dim3(256), 0, stream,
                       srcI, dstI, bcnt, ebuf, W1, W2, WT1, WT2);
    hipLaunchKernelGGL(k_build_csr, dim3(NB),      dim3(512), 0, stream, ebuf, bcnt, rowbeg, rowend, dinv, col);

    // layer 1 (gemm1 reads fp32 x directly; tail blocks zero `out`)
    hipLaunchKernelGGL(k_gemm_x,      dim3(GEMM_B + ZERO_B), dim3(256), 0, stream, x, WT1, dinv, Gh, out, out_size);
    hipLaunchKernelGGL(k_aggregate_c, dim3(AGG_B),           dim3(256), 0, stream, Gh, dinv, rowbeg, rowend, col, b1, H1h);

    // layer 2 + heads
    hipLaunchKernelGGL(k_gemm_h,            dim3(GEMM_B), dim3(256), 0, stream, H1h, WT2, dinv, Gh);
    hipLaunchKernelGGL(k_aggregate_heads_c, dim3(AGG_B),  dim3(256), 0, stream, Gh, dinv, rowbeg, rowend, col, b2,
                       Wt, bt, We, be, out);
}